// Round 1
// baseline (360.179 us; speedup 1.0000x reference)
//
#include <hip/hip_runtime.h>

#define Bb 2
#define Cc 64
#define Hh 48
#define Ww 48
#define Ll 48
#define HWc (Hh*Ww)          /* 2304 */
#define HWL (HWc*Ll)         /* 110592 */
#define GHh 24
#define SG (GHh*GHh*GHh)     /* 13824 */
#define NBLK (Bb*HWc)        /* 4608 */
#define CNT1f 110592.0f
#define CNT2f 9437184.0f     /* HW*C*C */

// half-pixel trilinear taps for 24 -> 48 (matches jax.image.resize 'trilinear')
__device__ __forceinline__ void interp1(int i, int& a, int& b, float& f){
  float src = i*0.5f - 0.25f;
  float fl = floorf(src);
  f = src - fl;
  int i0 = (int)fl;
  a = i0 < 0 ? 0 : i0;
  int i1 = i0 + 1;
  b = i1 > (GHh-1) ? (GHh-1) : i1;
}

// out[b,o,s] = sum_c W[o,c]*in[b,c,s] + bias[o]
__global__ __launch_bounds__(256) void conv_k(const float* __restrict__ in,
    const float* __restrict__ Wm, const float* __restrict__ bias,
    float* __restrict__ out, int S){
  __shared__ __align__(16) float Wl[64][68];   // Wl[c][o]
  __shared__ __align__(16) float xl[64][68];   // xl[c][s]
  int t = threadIdx.x;
  int ntile = S >> 6;
  int b  = blockIdx.x / ntile;
  int s0 = (blockIdx.x % ntile) << 6;
  for (int q = t; q < 4096; q += 256){
    int o = q >> 6, c = q & 63;
    Wl[c][o] = Wm[q];
  }
  const float* inb = in + (size_t)b*Cc*S + s0;
  for (int q = t; q < 1024; q += 256){
    int c = q >> 4, v = (q & 15) << 2;
    float4 val = *(const float4*)(inb + (size_t)c*S + v);
    *(float4*)&xl[c][v] = val;
  }
  __syncthreads();
  int o0 = (t & 15) << 2, s1 = (t >> 4) << 2;
  float a00=0,a01=0,a02=0,a03=0,a10=0,a11=0,a12=0,a13=0;
  float a20=0,a21=0,a22=0,a23=0,a30=0,a31=0,a32=0,a33=0;
  #pragma unroll 8
  for (int c = 0; c < 64; ++c){
    float4 wv = *(const float4*)&Wl[c][o0];
    float4 xv = *(const float4*)&xl[c][s1];
    a00 += wv.x*xv.x; a01 += wv.x*xv.y; a02 += wv.x*xv.z; a03 += wv.x*xv.w;
    a10 += wv.y*xv.x; a11 += wv.y*xv.y; a12 += wv.y*xv.z; a13 += wv.y*xv.w;
    a20 += wv.z*xv.x; a21 += wv.z*xv.y; a22 += wv.z*xv.z; a23 += wv.z*xv.w;
    a30 += wv.w*xv.x; a31 += wv.w*xv.y; a32 += wv.w*xv.z; a33 += wv.w*xv.w;
  }
  float* ob = out + (size_t)b*Cc*S + s0 + s1;
  float b0 = bias[o0+0], b1v = bias[o0+1], b2v = bias[o0+2], b3 = bias[o0+3];
  { float4 r = make_float4(a00+b0,a01+b0,a02+b0,a03+b0); *(float4*)(ob + (size_t)(o0+0)*S) = r; }
  { float4 r = make_float4(a10+b1v,a11+b1v,a12+b1v,a13+b1v); *(float4*)(ob + (size_t)(o0+1)*S) = r; }
  { float4 r = make_float4(a20+b2v,a21+b2v,a22+b2v,a23+b2v); *(float4*)(ob + (size_t)(o0+2)*S) = r; }
  { float4 r = make_float4(a30+b3,a31+b3,a32+b3,a33+b3); *(float4*)(ob + (size_t)(o0+3)*S) = r; }
}

// materialize full-resolution theta_g: (B,C,24^3) -> (B,C,48^3)
// one block per (b*C + c, h)
__global__ __launch_bounds__(256) void upsample_k(const float* __restrict__ tgh,
    float* __restrict__ tg){
  __shared__ float shm[2][24][25];
  int t = threadIdx.x;
  int bc = blockIdx.x / Hh;
  int h  = blockIdx.x % Hh;
  int ha, hb; float fh; interp1(h, ha, hb, fh);
  const float* src = tgh + (size_t)bc*SG;
  for (int q = t; q < 288; q += 256){
    int p = q / 144, rem = q % 144;
    int w_ = rem / 6, vl = (rem % 6) << 2;
    int hs = p ? hb : ha;
    float4 v = *(const float4*)(src + (size_t)hs*576 + w_*24 + vl);
    shm[p][w_][vl+0]=v.x; shm[p][w_][vl+1]=v.y; shm[p][w_][vl+2]=v.z; shm[p][w_][vl+3]=v.w;
  }
  __syncthreads();
  float* dst = tg + ((size_t)bc*Hh + h)*HWc;
  float omf = 1.f - fh;
  #pragma unroll
  for (int k = 0; k < 9; ++k){
    int idx = t + (k << 8);          // 0..2303
    int w = idx / 48, l = idx % 48;
    int wa, wb; float fw; interp1(w, wa, wb, fw);
    int la, lb; float fl; interp1(l, la, lb, fl);
    float vaa = omf*shm[0][wa][la] + fh*shm[1][wa][la];
    float vab = omf*shm[0][wa][lb] + fh*shm[1][wa][lb];
    float vba = omf*shm[0][wb][la] + fh*shm[1][wb][la];
    float vbb = omf*shm[0][wb][lb] + fh*shm[1][wb][lb];
    float va = (1.f-fw)*vaa + fw*vba;
    float vb = (1.f-fw)*vab + fw*vbb;
    dst[idx] = (1.f-fl)*va + fl*vb;
  }
}

// one block per (b,h,w): per-block partials (no global atomics)
// NEW: also stores the raw At = tx^T*tg (C x C) tile to global (Atg) so
// final2_k does not have to recompute it. Stores are per-thread register
// float4s; lanes {t, t+16, t+32, t+48} cover one contiguous 64B line.
__global__ __launch_bounds__(256) void reduce_k(const float* __restrict__ tx,
    const float* __restrict__ tg, float* __restrict__ part_row,
    float* __restrict__ pm1, float* __restrict__ pm2, float* __restrict__ ps2,
    float* __restrict__ Atg){
  __shared__ __align__(16) float txt[48][68];   // [l][c]
  __shared__ __align__(16) float tgt[48][68];   // [l][c]
  __shared__ float red[512];
  __shared__ float sxg[48];
  int t = threadIdx.x;
  int bIdx = blockIdx.x;
  int b = bIdx / HWc, hw = bIdx % HWc;
  const float* txb = tx + ((size_t)b*Cc*HWc + hw)*Ll;
  const float* tgb = tg + ((size_t)b*Cc*HWc + hw)*Ll;
  for (int q = t; q < 768; q += 256){
    int c = q / 12, v = (q % 12) << 2;
    float4 a = *(const float4*)(txb + (size_t)c*HWL + v);
    txt[v+0][c]=a.x; txt[v+1][c]=a.y; txt[v+2][c]=a.z; txt[v+3][c]=a.w;
    float4 g = *(const float4*)(tgb + (size_t)c*HWL + v);
    tgt[v+0][c]=g.x; tgt[v+1][c]=g.y; tgt[v+2][c]=g.z; tgt[v+3][c]=g.w;
  }
  __syncthreads();
  int c = t & 63, lg = t >> 6;
  float psum = 0.f, pmin = 3.4e38f;
  #pragma unroll
  for (int li = 0; li < 12; ++li){
    int l = lg*12 + li;
    float prod = txt[l][c]*tgt[l][c];
    psum += prod;
    pmin = fminf(pmin, prod);
  }
  red[t] = psum;
  if (t < 48){
    float sx = 0.f, sg = 0.f;
    #pragma unroll 8
    for (int cc = 0; cc < 64; ++cc){ sx += txt[t][cc]; sg += tgt[t][cc]; }
    sxg[t] = sx*sg;
  }
  __syncthreads();
  if (t < 64) part_row[(size_t)bIdx*64 + t] = red[t]+red[t+64]+red[t+128]+red[t+192];
  // raw theta_c_d[i,j] = sum_l txt[l][i]*tgt[l][j]; block min
  int i0 = (t & 15) << 2, j0 = (t >> 4) << 2;
  float a00=0,a01=0,a02=0,a03=0,a10=0,a11=0,a12=0,a13=0;
  float a20=0,a21=0,a22=0,a23=0,a30=0,a31=0,a32=0,a33=0;
  #pragma unroll 4
  for (int l = 0; l < 48; ++l){
    float4 av = *(const float4*)&txt[l][i0];
    float4 bv = *(const float4*)&tgt[l][j0];
    a00 += av.x*bv.x; a01 += av.x*bv.y; a02 += av.x*bv.z; a03 += av.x*bv.w;
    a10 += av.y*bv.x; a11 += av.y*bv.y; a12 += av.y*bv.z; a13 += av.y*bv.w;
    a20 += av.z*bv.x; a21 += av.z*bv.y; a22 += av.z*bv.z; a23 += av.z*bv.w;
    a30 += av.w*bv.x; a31 += av.w*bv.y; a32 += av.w*bv.z; a33 += av.w*bv.w;
  }
  float amin = fminf(fminf(fminf(a00,a01),fminf(a02,a03)),
               fminf(fminf(fminf(a10,a11),fminf(a12,a13)),
               fminf(fminf(fminf(a20,a21),fminf(a22,a23)),
                     fminf(fminf(a30,a31),fminf(a32,a33)))));
  if (Atg){
    float* ab = Atg + (size_t)bIdx*4096 + (size_t)i0*64 + j0;
    { float4 r = make_float4(a00,a01,a02,a03); *(float4*)(ab +   0) = r; }
    { float4 r = make_float4(a10,a11,a12,a13); *(float4*)(ab +  64) = r; }
    { float4 r = make_float4(a20,a21,a22,a23); *(float4*)(ab + 128) = r; }
    { float4 r = make_float4(a30,a31,a32,a33); *(float4*)(ab + 192) = r; }
  }
  __syncthreads();            // red reads (part_row) done
  red[t] = pmin; red[256+t] = amin;
  __syncthreads();
  if (t < 128){
    red[t] = fminf(red[t], red[t+128]);
    red[256+t] = fminf(red[256+t], red[256+t+128]);
  }
  __syncthreads();
  if (t < 64){
    float v1 = fminf(red[t], red[t+64]);
    float v2 = fminf(red[256+t], red[256+t+64]);
    #pragma unroll
    for (int off = 32; off; off >>= 1){
      v1 = fminf(v1, __shfl_down(v1, off));
      v2 = fminf(v2, __shfl_down(v2, off));
    }
    if (t == 0){
      pm1[bIdx] = v1; pm2[bIdx] = v2;
      float tot = 0.f;
      #pragma unroll
      for (int l = 0; l < 48; ++l) tot += sxg[l];
      ps2[bIdx] = tot;
    }
  }
}

// parallel second-stage reduction: 130 blocks
__global__ __launch_bounds__(256) void reduce2_k(const float* __restrict__ part_row,
    const float* __restrict__ pm1, const float* __restrict__ pm2,
    const float* __restrict__ ps2, float* __restrict__ rowsum,
    float* __restrict__ gmin, float* __restrict__ s2v){
  __shared__ float red[512];
  int t = threadIdx.x, blk = blockIdx.x;
  if (blk < 128){
    int b = blk >> 6, c = blk & 63;
    const float* src = part_row + (size_t)b*HWc*64 + c;
    float s = 0.f;
    #pragma unroll
    for (int k = 0; k < 9; ++k){
      int i = t + (k << 8);
      s += src[(size_t)i*64];
    }
    red[t] = s; __syncthreads();
    for (int sgap = 128; sgap >= 64; sgap >>= 1){
      if (t < sgap) red[t] += red[t+sgap];
      __syncthreads();
    }
    if (t < 64){
      float v = red[t];
      #pragma unroll
      for (int off = 32; off; off >>= 1) v += __shfl_down(v, off);
      if (t == 0) rowsum[blk] = v;
    }
  } else if (blk == 128){
    float m1 = 3.4e38f, m2 = 3.4e38f;
    for (int i = t; i < NBLK; i += 256){ m1 = fminf(m1, pm1[i]); m2 = fminf(m2, pm2[i]); }
    red[t] = m1; red[256+t] = m2; __syncthreads();
    for (int s = 128; s >= 1; s >>= 1){
      if (t < s){ red[t] = fminf(red[t], red[t+s]); red[256+t] = fminf(red[256+t], red[256+t+s]); }
      __syncthreads();
    }
    if (t == 0){ gmin[0] = red[0]; gmin[1] = red[256]; }
  } else {
    float sa = 0.f, sb = 0.f;
    for (int i = t; i < HWc; i += 256){ sa += ps2[i]; sb += ps2[HWc + i]; }
    red[t] = sa; red[256+t] = sb; __syncthreads();
    for (int s = 128; s >= 1; s >>= 1){
      if (t < s){ red[t] += red[t+s]; red[256+t] += red[256+t+s]; }
      __syncthreads();
    }
    if (t == 0){ s2v[0] = red[0]; s2v[1] = red[256]; }
  }
}

// NEW final: consumes the stored At. No LDS transposes at all.
//  p = (tx*tg - m1)*iv1[c]*x  : pure streaming (tx/tg from global, L3-hot)
//  d[j,l] = invd2 * sum_c (At[c][j]-m2)*x[c][l]   (m2 folded into At staging,
//           which algebraically eliminates the Xs[l] column-sum phase)
// LDS 30976B -> 5 blocks/CU (vs 39936B/4 before); one __syncthreads total.
__global__ __launch_bounds__(256) void final2_k(const float* __restrict__ x,
    const float* __restrict__ tx, const float* __restrict__ tg,
    const float* __restrict__ Atg, const float* __restrict__ gmin,
    const float* __restrict__ rowsum, const float* __restrict__ s2v,
    float* __restrict__ outp, float* __restrict__ outd){
  __shared__ __align__(16) float xs[64][52];    // x, native [c][l] layout
  __shared__ __align__(16) float AtL[64][68];   // At - m2, [c][j]
  __shared__ float iv1[64];
  int t = threadIdx.x;
  int bIdx = blockIdx.x;
  int b = bIdx / HWc, hw = bIdx % HWc;
  size_t sbase = ((size_t)b*Cc*HWc + hw)*Ll;
  const float* xb = x + sbase;
  float m1 = gmin[0], m2 = gmin[1];
  for (int q = t; q < 768; q += 256){
    int c = q / 12, v = (q % 12) << 2;
    *(float4*)&xs[c][v] = *(const float4*)(xb + (size_t)c*HWL + v);
  }
  const float* ab = Atg + (size_t)bIdx*4096;
  for (int q = t; q < 1024; q += 256){
    float4 a = *(const float4*)(ab + (q << 2));
    int i = q >> 4, j = (q & 15) << 2;
    a.x -= m2; a.y -= m2; a.z -= m2; a.w -= m2;
    *(float4*)&AtL[i][j] = a;
  }
  if (t < 64) iv1[t] = 1.f/(rowsum[b*64 + t] - m1*CNT1f);
  float invd2 = 1.f/(s2v[b] - m2*CNT2f);
  __syncthreads();
  // p: all 256 threads, pure streaming
  #pragma unroll
  for (int k = 0; k < 3; ++k){
    int f = t + (k << 8);
    int c = f / 12, l4 = (f % 12) << 2;
    size_t off = sbase + (size_t)c*HWL + l4;
    float4 a = *(const float4*)(tx + off);
    float4 g = *(const float4*)(tg + off);
    float4 xv = *(const float4*)&xs[c][l4];
    float s = iv1[c];
    float4 r = make_float4((a.x*g.x - m1)*s*xv.x, (a.y*g.y - m1)*s*xv.y,
                           (a.z*g.z - m1)*s*xv.z, (a.w*g.w - m1)*s*xv.w);
    *(float4*)(outp + off) = r;
  }
  // d: 192 threads, 4x4 register tile; conflict-free LDS reads
  if (t < 192){
    int jj = (t & 15) << 2, l0 = (t >> 4) << 2;
    float d00=0,d01=0,d02=0,d03=0,d10=0,d11=0,d12=0,d13=0;
    float d20=0,d21=0,d22=0,d23=0,d30=0,d31=0,d32=0,d33=0;
    #pragma unroll 4
    for (int cc = 0; cc < 64; ++cc){
      float4 av = *(const float4*)&AtL[cc][jj];
      float4 xv = *(const float4*)&xs[cc][l0];
      d00 += av.x*xv.x; d01 += av.x*xv.y; d02 += av.x*xv.z; d03 += av.x*xv.w;
      d10 += av.y*xv.x; d11 += av.y*xv.y; d12 += av.y*xv.z; d13 += av.y*xv.w;
      d20 += av.z*xv.x; d21 += av.z*xv.y; d22 += av.z*xv.z; d23 += av.z*xv.w;
      d30 += av.w*xv.x; d31 += av.w*xv.y; d32 += av.w*xv.z; d33 += av.w*xv.w;
    }
    { float4 r = make_float4(d00*invd2,d01*invd2,d02*invd2,d03*invd2);
      *(float4*)(outd + sbase + (size_t)(jj+0)*HWL + l0) = r; }
    { float4 r = make_float4(d10*invd2,d11*invd2,d12*invd2,d13*invd2);
      *(float4*)(outd + sbase + (size_t)(jj+1)*HWL + l0) = r; }
    { float4 r = make_float4(d20*invd2,d21*invd2,d22*invd2,d23*invd2);
      *(float4*)(outd + sbase + (size_t)(jj+2)*HWL + l0) = r; }
    { float4 r = make_float4(d30*invd2,d31*invd2,d32*invd2,d33*invd2);
      *(float4*)(outd + sbase + (size_t)(jj+3)*HWL + l0) = r; }
  }
}

// FALLBACK final (original): used only if ws is too small to hold At.
__global__ __launch_bounds__(256) void final_k(const float* __restrict__ x,
    const float* __restrict__ tx, const float* __restrict__ tg,
    const float* __restrict__ gmin, const float* __restrict__ rowsum,
    const float* __restrict__ s2v, float* __restrict__ outp, float* __restrict__ outd){
  __shared__ __align__(16) float sh[6528 + 3328 + 48 + 64];
  float* txt = sh;
  float* tgt = sh + 3264;
  float* At  = sh;
  float* xs  = sh + 6528;
  float* Xs  = sh + 6528 + 3328;
  float* iv1 = Xs + 48;
  int t = threadIdx.x;
  int bIdx = blockIdx.x;
  int b = bIdx / HWc, hw = bIdx % HWc;
  size_t sbase = ((size_t)b*Cc*HWc + hw)*Ll;
  const float* txb = tx + sbase;
  const float* tgb = tg + sbase;
  const float* xb  = x  + sbase;
  for (int q = t; q < 768; q += 256){
    int c = q / 12, v = (q % 12) << 2;
    float4 a = *(const float4*)(txb + (size_t)c*HWL + v);
    txt[(v+0)*68+c]=a.x; txt[(v+1)*68+c]=a.y; txt[(v+2)*68+c]=a.z; txt[(v+3)*68+c]=a.w;
    float4 g = *(const float4*)(tgb + (size_t)c*HWL + v);
    tgt[(v+0)*68+c]=g.x; tgt[(v+1)*68+c]=g.y; tgt[(v+2)*68+c]=g.z; tgt[(v+3)*68+c]=g.w;
    float4 xv = *(const float4*)(xb + (size_t)c*HWL + v);
    *(float4*)&xs[c*52 + v] = xv;
  }
  __syncthreads();
  if (t < 48){
    float s = 0.f;
    #pragma unroll 8
    for (int cc = 0; cc < 64; ++cc) s += xs[cc*52 + t];
    Xs[t] = s;
  }
  float m1 = gmin[0], m2 = gmin[1];
  if (t < 64) iv1[t] = 1.f/(rowsum[b*64 + t] - m1*CNT1f);
  float invd2 = 1.f/(s2v[b] - m2*CNT2f);
  int i0 = (t & 15) << 2, j0 = (t >> 4) << 2;
  float a00=0,a01=0,a02=0,a03=0,a10=0,a11=0,a12=0,a13=0;
  float a20=0,a21=0,a22=0,a23=0,a30=0,a31=0,a32=0,a33=0;
  #pragma unroll 4
  for (int l = 0; l < 48; ++l){
    float4 av = *(const float4*)&txt[l*68 + i0];
    float4 bv = *(const float4*)&tgt[l*68 + j0];
    a00 += av.x*bv.x; a01 += av.x*bv.y; a02 += av.x*bv.z; a03 += av.x*bv.w;
    a10 += av.y*bv.x; a11 += av.y*bv.y; a12 += av.y*bv.z; a13 += av.y*bv.w;
    a20 += av.z*bv.x; a21 += av.z*bv.y; a22 += av.z*bv.z; a23 += av.z*bv.w;
    a30 += av.w*bv.x; a31 += av.w*bv.y; a32 += av.w*bv.z; a33 += av.w*bv.w;
  }
  __syncthreads();
  #pragma unroll
  for (int k = 0; k < 12; ++k){
    int e = t + (k << 8);
    int cc = e / 48, l = e % 48;
    float pv = (txt[l*68+cc]*tgt[l*68+cc] - m1)*iv1[cc]*xs[cc*52+l];
    outp[sbase + (size_t)cc*HWL + l] = pv;
  }
  __syncthreads();
  { float4 r = make_float4(a00,a01,a02,a03); *(float4*)&At[(i0+0)*68 + j0] = r; }
  { float4 r = make_float4(a10,a11,a12,a13); *(float4*)&At[(i0+1)*68 + j0] = r; }
  { float4 r = make_float4(a20,a21,a22,a23); *(float4*)&At[(i0+2)*68 + j0] = r; }
  { float4 r = make_float4(a30,a31,a32,a33); *(float4*)&At[(i0+3)*68 + j0] = r; }
  __syncthreads();
  if (t < 192){
    int jj = (t & 15) << 2, l0 = (t >> 4) << 2;
    float d00=0,d01=0,d02=0,d03=0,d10=0,d11=0,d12=0,d13=0;
    float d20=0,d21=0,d22=0,d23=0,d30=0,d31=0,d32=0,d33=0;
    #pragma unroll 4
    for (int cc = 0; cc < 64; ++cc){
      float4 av = *(const float4*)&At[cc*68 + jj];
      float4 xv = *(const float4*)&xs[cc*52 + l0];
      d00 += av.x*xv.x; d01 += av.x*xv.y; d02 += av.x*xv.z; d03 += av.x*xv.w;
      d10 += av.y*xv.x; d11 += av.y*xv.y; d12 += av.y*xv.z; d13 += av.y*xv.w;
      d20 += av.z*xv.x; d21 += av.z*xv.y; d22 += av.z*xv.z; d23 += av.z*xv.w;
      d30 += av.w*xv.x; d31 += av.w*xv.y; d32 += av.w*xv.z; d33 += av.w*xv.w;
    }
    float xs0 = m2*Xs[l0+0], xs1 = m2*Xs[l0+1], xs2 = m2*Xs[l0+2], xs3 = m2*Xs[l0+3];
    { float4 r = make_float4((d00-xs0)*invd2,(d01-xs1)*invd2,(d02-xs2)*invd2,(d03-xs3)*invd2);
      *(float4*)(outd + sbase + (size_t)(jj+0)*HWL + l0) = r; }
    { float4 r = make_float4((d10-xs0)*invd2,(d11-xs1)*invd2,(d12-xs2)*invd2,(d13-xs3)*invd2);
      *(float4*)(outd + sbase + (size_t)(jj+1)*HWL + l0) = r; }
    { float4 r = make_float4((d20-xs0)*invd2,(d21-xs1)*invd2,(d22-xs2)*invd2,(d23-xs3)*invd2);
      *(float4*)(outd + sbase + (size_t)(jj+2)*HWL + l0) = r; }
    { float4 r = make_float4((d30-xs0)*invd2,(d31-xs1)*invd2,(d32-xs2)*invd2,(d33-xs3)*invd2);
      *(float4*)(outd + sbase + (size_t)(jj+3)*HWL + l0) = r; }
  }
}

extern "C" void kernel_launch(void* const* d_in, const int* in_sizes, int n_in,
                              void* d_out, int out_size, void* d_ws, size_t ws_size,
                              hipStream_t stream){
  (void)in_sizes; (void)n_in; (void)out_size;
  const float* x  = (const float*)d_in[0];
  const float* g  = (const float*)d_in[1];
  const float* W1 = (const float*)d_in[2];
  const float* b1 = (const float*)d_in[3];
  const float* W2 = (const float*)d_in[4];
  const float* b2 = (const float*)d_in[5];
  float* outp = (float*)d_out;
  float* outd = outp + (size_t)Bb*Cc*HWL;
  float* ws   = (float*)d_ws;
  float* txw  = ws;
  float* tgw  = txw + (size_t)Bb*Cc*HWL;
  float* tghw = tgw + (size_t)Bb*Cc*HWL;
  float* part_row = tghw + (size_t)Bb*Cc*SG;
  float* pm1 = part_row + (size_t)NBLK*64;
  float* pm2 = pm1 + NBLK;
  float* ps2 = pm2 + NBLK;
  float* rowsum = ps2 + NBLK;
  float* gmin = rowsum + 128;
  float* s2v  = gmin + 2;
  float* Atg  = s2v + 2;                          // NBLK*4096 floats = 75.5 MB

  size_t base_floats = (size_t)Bb*Cc*HWL*2 + (size_t)Bb*Cc*SG + (size_t)NBLK*64
                     + 3*(size_t)NBLK + 128 + 4;
  size_t need_bytes = (base_floats + (size_t)NBLK*4096) * sizeof(float);
  int useAt = (ws_size >= need_bytes);

  hipLaunchKernelGGL(conv_k, dim3(Bb*(SG/64)), dim3(256), 0, stream, g, W2, b2, tghw, SG);
  hipLaunchKernelGGL(conv_k, dim3(Bb*(HWL/64)), dim3(256), 0, stream, x, W1, b1, txw, HWL);
  hipLaunchKernelGGL(upsample_k, dim3(Bb*Cc*Hh), dim3(256), 0, stream, tghw, tgw);
  hipLaunchKernelGGL(reduce_k, dim3(NBLK), dim3(256), 0, stream, txw, tgw, part_row,
                     pm1, pm2, ps2, useAt ? Atg : (float*)nullptr);
  hipLaunchKernelGGL(reduce2_k, dim3(130), dim3(256), 0, stream, part_row, pm1, pm2, ps2,
                     rowsum, gmin, s2v);
  if (useAt)
    hipLaunchKernelGGL(final2_k, dim3(NBLK), dim3(256), 0, stream, x, txw, tgw, Atg,
                       gmin, rowsum, s2v, outp, outd);
  else
    hipLaunchKernelGGL(final_k, dim3(NBLK), dim3(256), 0, stream, x, txw, tgw,
                       gmin, rowsum, s2v, outp, outd);
}

// Round 2
// 330.871 us; speedup vs baseline: 1.0886x; 1.0886x over previous
//
#include <hip/hip_runtime.h>

#define Bb 2
#define Cc 64
#define Hh 48
#define Ww 48
#define Ll 48
#define HWc (Hh*Ww)          /* 2304 */
#define HWL (HWc*Ll)         /* 110592 */
#define GHh 24
#define SG (GHh*GHh*GHh)     /* 13824 */
#define NBLK (Bb*HWc)        /* 4608 */
#define CNT1f 110592.0f
#define CNT2f 9437184.0f     /* HW*C*C */

// half-pixel trilinear taps for 24 -> 48 (matches jax.image.resize 'trilinear')
__device__ __forceinline__ void interp1(int i, int& a, int& b, float& f){
  float src = i*0.5f - 0.25f;
  float fl = floorf(src);
  f = src - fl;
  int i0 = (int)fl;
  a = i0 < 0 ? 0 : i0;
  int i1 = i0 + 1;
  b = i1 > (GHh-1) ? (GHh-1) : i1;
}

// out[b,o,s] = sum_c W[o,c]*in[b,c,s] + bias[o]
__global__ __launch_bounds__(256) void conv_k(const float* __restrict__ in,
    const float* __restrict__ Wm, const float* __restrict__ bias,
    float* __restrict__ out, int S){
  __shared__ __align__(16) float Wl[64][68];   // Wl[c][o]
  __shared__ __align__(16) float xl[64][68];   // xl[c][s]
  int t = threadIdx.x;
  int ntile = S >> 6;
  int b  = blockIdx.x / ntile;
  int s0 = (blockIdx.x % ntile) << 6;
  for (int q = t; q < 4096; q += 256){
    int o = q >> 6, c = q & 63;
    Wl[c][o] = Wm[q];
  }
  const float* inb = in + (size_t)b*Cc*S + s0;
  for (int q = t; q < 1024; q += 256){
    int c = q >> 4, v = (q & 15) << 2;
    float4 val = *(const float4*)(inb + (size_t)c*S + v);
    *(float4*)&xl[c][v] = val;
  }
  __syncthreads();
  int o0 = (t & 15) << 2, s1 = (t >> 4) << 2;
  float a00=0,a01=0,a02=0,a03=0,a10=0,a11=0,a12=0,a13=0;
  float a20=0,a21=0,a22=0,a23=0,a30=0,a31=0,a32=0,a33=0;
  #pragma unroll 8
  for (int c = 0; c < 64; ++c){
    float4 wv = *(const float4*)&Wl[c][o0];
    float4 xv = *(const float4*)&xl[c][s1];
    a00 += wv.x*xv.x; a01 += wv.x*xv.y; a02 += wv.x*xv.z; a03 += wv.x*xv.w;
    a10 += wv.y*xv.x; a11 += wv.y*xv.y; a12 += wv.y*xv.z; a13 += wv.y*xv.w;
    a20 += wv.z*xv.x; a21 += wv.z*xv.y; a22 += wv.z*xv.z; a23 += wv.z*xv.w;
    a30 += wv.w*xv.x; a31 += wv.w*xv.y; a32 += wv.w*xv.z; a33 += wv.w*xv.w;
  }
  float* ob = out + (size_t)b*Cc*S + s0 + s1;
  float b0 = bias[o0+0], b1v = bias[o0+1], b2v = bias[o0+2], b3 = bias[o0+3];
  { float4 r = make_float4(a00+b0,a01+b0,a02+b0,a03+b0); *(float4*)(ob + (size_t)(o0+0)*S) = r; }
  { float4 r = make_float4(a10+b1v,a11+b1v,a12+b1v,a13+b1v); *(float4*)(ob + (size_t)(o0+1)*S) = r; }
  { float4 r = make_float4(a20+b2v,a21+b2v,a22+b2v,a23+b2v); *(float4*)(ob + (size_t)(o0+2)*S) = r; }
  { float4 r = make_float4(a30+b3,a31+b3,a32+b3,a33+b3); *(float4*)(ob + (size_t)(o0+3)*S) = r; }
}

// one block per (b,h,w) site.
// Fuses the trilinear upsample (reads half-res tgh, L2/L3-resident 7MB),
// writes the site tile tgsite[bIdx][c][48] contiguous for final_k, and
// computes all per-site partials (rowsum per c, mins, s2 correction).
__global__ __launch_bounds__(256) void reduce_k(const float* __restrict__ tx,
    const float* __restrict__ tgh, float* __restrict__ tgsite,
    float* __restrict__ part_row, float* __restrict__ pm1,
    float* __restrict__ pm2, float* __restrict__ ps2){
  __shared__ __align__(16) float txt[64*52];   // [c][52]
  __shared__ __align__(16) float tgt[64*52];   // [c][52]
  __shared__ float Msh[64*25];                 // bilinear(h,w) rows, [c][25]
  __shared__ float red[512];
  __shared__ float sxg[48];
  int t = threadIdx.x;
  int bIdx = blockIdx.x;
  int b = bIdx / HWc, hw = bIdx % HWc;
  int h = hw / Ww, w = hw % Ww;
  int ha, hb; float fh; interp1(h, ha, hb, fh);
  int wa, wb; float fw; interp1(w, wa, wb, fw);
  float omh = 1.f - fh, omw = 1.f - fw;
  // stage txt (gathered 192B rows), conflict-free float4
  const float* txb = tx + ((size_t)b*Cc*HWc + hw)*Ll;
  #pragma unroll
  for (int k = 0; k < 3; ++k){
    int q = t + (k << 8);
    int c = q / 12, v = (q % 12) << 2;
    *(float4*)&txt[c*52+v] = *(const float4*)(txb + (size_t)c*HWL + v);
  }
  // M[c][j] = bilinear over (h,w) of tgh taps; same lerp order as the old
  // upsample kernel (h first, then w) for bit-compatibility.
  const float* gb = tgh + (size_t)b*Cc*SG;
  #pragma unroll
  for (int k = 0; k < 6; ++k){
    int q = t + (k << 8);
    int c = q / 24, j = q % 24;
    const float* gc = gb + (size_t)c*SG;
    float vaa = gc[ha*576 + wa*24 + j];
    float vba = gc[hb*576 + wa*24 + j];
    float vab = gc[ha*576 + wb*24 + j];
    float vbb = gc[hb*576 + wb*24 + j];
    float mwa = omh*vaa + fh*vba;
    float mwb = omh*vab + fh*vbb;
    Msh[c*25 + j] = omw*mwa + fw*mwb;
  }
  __syncthreads();
  // expand along l -> tgt, and store site-major to global for final_k
  float* tgs = tgsite + (size_t)bIdx*3072;
  #pragma unroll
  for (int k = 0; k < 3; ++k){
    int q = t + (k << 8);
    int c = q / 12, l4 = (q % 12) << 2;
    float4 r;
    float* rp = &r.x;
    #pragma unroll
    for (int i = 0; i < 4; ++i){
      int l = l4 + i;
      int la, lb; float fl; interp1(l, la, lb, fl);
      rp[i] = (1.f-fl)*Msh[c*25+la] + fl*Msh[c*25+lb];
    }
    *(float4*)&tgt[c*52+l4] = r;
    *(float4*)(tgs + c*48 + l4) = r;
  }
  __syncthreads();
  // per-channel product sums + global min of products
  int c = t & 63, lq = t >> 6;
  float psum = 0.f, pmin = 3.4e38f;
  #pragma unroll
  for (int m = 0; m < 3; ++m){
    int l4 = (lq << 2) + (m << 4);
    float4 a = *(const float4*)&txt[c*52+l4];
    float4 g = *(const float4*)&tgt[c*52+l4];
    float p0 = a.x*g.x, p1 = a.y*g.y, p2 = a.z*g.z, p3 = a.w*g.w;
    psum += p0+p1+p2+p3;
    pmin = fminf(pmin, fminf(fminf(p0,p1), fminf(p2,p3)));
  }
  red[t] = psum;
  if (t < 48){
    float sx = 0.f, sg = 0.f;
    #pragma unroll 8
    for (int cc = 0; cc < 64; ++cc){ sx += txt[cc*52+t]; sg += tgt[cc*52+t]; }
    sxg[t] = sx*sg;
  }
  // At[i][j] = sum_l txt[i][l]*tgt[j][l]: 4x4 tile per thread, block min only
  int i0 = (t & 15) << 2, j0 = (t >> 4) << 2;
  float a00=0,a01=0,a02=0,a03=0,a10=0,a11=0,a12=0,a13=0;
  float a20=0,a21=0,a22=0,a23=0,a30=0,a31=0,a32=0,a33=0;
  #pragma unroll 4
  for (int l0 = 0; l0 < 48; l0 += 4){
    float4 x0 = *(const float4*)&txt[(i0+0)*52 + l0];
    float4 x1 = *(const float4*)&txt[(i0+1)*52 + l0];
    float4 x2 = *(const float4*)&txt[(i0+2)*52 + l0];
    float4 x3 = *(const float4*)&txt[(i0+3)*52 + l0];
    float4 g0 = *(const float4*)&tgt[(j0+0)*52 + l0];
    float4 g1 = *(const float4*)&tgt[(j0+1)*52 + l0];
    float4 g2 = *(const float4*)&tgt[(j0+2)*52 + l0];
    float4 g3 = *(const float4*)&tgt[(j0+3)*52 + l0];
    a00 += x0.x*g0.x + x0.y*g0.y + x0.z*g0.z + x0.w*g0.w;
    a01 += x0.x*g1.x + x0.y*g1.y + x0.z*g1.z + x0.w*g1.w;
    a02 += x0.x*g2.x + x0.y*g2.y + x0.z*g2.z + x0.w*g2.w;
    a03 += x0.x*g3.x + x0.y*g3.y + x0.z*g3.z + x0.w*g3.w;
    a10 += x1.x*g0.x + x1.y*g0.y + x1.z*g0.z + x1.w*g0.w;
    a11 += x1.x*g1.x + x1.y*g1.y + x1.z*g1.z + x1.w*g1.w;
    a12 += x1.x*g2.x + x1.y*g2.y + x1.z*g2.z + x1.w*g2.w;
    a13 += x1.x*g3.x + x1.y*g3.y + x1.z*g3.z + x1.w*g3.w;
    a20 += x2.x*g0.x + x2.y*g0.y + x2.z*g0.z + x2.w*g0.w;
    a21 += x2.x*g1.x + x2.y*g1.y + x2.z*g1.z + x2.w*g1.w;
    a22 += x2.x*g2.x + x2.y*g2.y + x2.z*g2.z + x2.w*g2.w;
    a23 += x2.x*g3.x + x2.y*g3.y + x2.z*g3.z + x2.w*g3.w;
    a30 += x3.x*g0.x + x3.y*g0.y + x3.z*g0.z + x3.w*g0.w;
    a31 += x3.x*g1.x + x3.y*g1.y + x3.z*g1.z + x3.w*g1.w;
    a32 += x3.x*g2.x + x3.y*g2.y + x3.z*g2.z + x3.w*g2.w;
    a33 += x3.x*g3.x + x3.y*g3.y + x3.z*g3.z + x3.w*g3.w;
  }
  float amin = fminf(fminf(fminf(a00,a01),fminf(a02,a03)),
               fminf(fminf(fminf(a10,a11),fminf(a12,a13)),
               fminf(fminf(fminf(a20,a21),fminf(a22,a23)),
                     fminf(fminf(a30,a31),fminf(a32,a33)))));
  __syncthreads();            // red (psum) fully written
  if (t < 64) part_row[(size_t)bIdx*64 + t] = red[t]+red[t+64]+red[t+128]+red[t+192];
  __syncthreads();            // part_row reads done before red reuse
  red[t] = pmin; red[256+t] = amin;
  __syncthreads();
  if (t < 128){
    red[t] = fminf(red[t], red[t+128]);
    red[256+t] = fminf(red[256+t], red[384+t]);
  }
  __syncthreads();
  if (t < 64){
    float v1 = fminf(red[t], red[t+64]);
    float v2 = fminf(red[256+t], red[320+t]);
    #pragma unroll
    for (int off = 32; off; off >>= 1){
      v1 = fminf(v1, __shfl_down(v1, off));
      v2 = fminf(v2, __shfl_down(v2, off));
    }
    if (t == 0){
      pm1[bIdx] = v1; pm2[bIdx] = v2;
      float tot = 0.f;
      #pragma unroll
      for (int l = 0; l < 48; ++l) tot += sxg[l];
      ps2[bIdx] = tot;
    }
  }
}

// parallel second-stage reduction: 130 blocks (unchanged)
__global__ __launch_bounds__(256) void reduce2_k(const float* __restrict__ part_row,
    const float* __restrict__ pm1, const float* __restrict__ pm2,
    const float* __restrict__ ps2, float* __restrict__ rowsum,
    float* __restrict__ gmin, float* __restrict__ s2v){
  __shared__ float red[512];
  int t = threadIdx.x, blk = blockIdx.x;
  if (blk < 128){
    int b = blk >> 6, c = blk & 63;
    const float* src = part_row + (size_t)b*HWc*64 + c;
    float s = 0.f;
    #pragma unroll
    for (int k = 0; k < 9; ++k){
      int i = t + (k << 8);
      s += src[(size_t)i*64];
    }
    red[t] = s; __syncthreads();
    for (int sgap = 128; sgap >= 64; sgap >>= 1){
      if (t < sgap) red[t] += red[t+sgap];
      __syncthreads();
    }
    if (t < 64){
      float v = red[t];
      #pragma unroll
      for (int off = 32; off; off >>= 1) v += __shfl_down(v, off);
      if (t == 0) rowsum[blk] = v;
    }
  } else if (blk == 128){
    float m1 = 3.4e38f, m2 = 3.4e38f;
    for (int i = t; i < NBLK; i += 256){ m1 = fminf(m1, pm1[i]); m2 = fminf(m2, pm2[i]); }
    red[t] = m1; red[256+t] = m2; __syncthreads();
    for (int s = 128; s >= 1; s >>= 1){
      if (t < s){ red[t] = fminf(red[t], red[t+s]); red[256+t] = fminf(red[256+t], red[256+t+s]); }
      __syncthreads();
    }
    if (t == 0){ gmin[0] = red[0]; gmin[1] = red[256]; }
  } else {
    float sa = 0.f, sb = 0.f;
    for (int i = t; i < HWc; i += 256){ sa += ps2[i]; sb += ps2[HWc + i]; }
    red[t] = sa; red[256+t] = sb; __syncthreads();
    for (int s = 128; s >= 1; s >>= 1){
      if (t < s){ red[t] += red[t+s]; red[256+t] += red[256+t+s]; }
      __syncthreads();
    }
    if (t == 0){ s2v[0] = red[0]; s2v[1] = red[256]; }
  }
}

// one block per (b,h,w): compute p and d.
// All tiles c-major [64][52]; tgt load is contiguous (site-major from reduce_k);
// At recomputed in registers (no global round-trip), scaled by invd2 at store.
__global__ __launch_bounds__(256) void final_k(const float* __restrict__ x,
    const float* __restrict__ tx, const float* __restrict__ tgsite,
    const float* __restrict__ gmin, const float* __restrict__ rowsum,
    const float* __restrict__ s2v, float* __restrict__ outp, float* __restrict__ outd){
  __shared__ __align__(16) float txt[64*52];   // aliased by At' after p
  __shared__ __align__(16) float tgt[64*52];
  __shared__ __align__(16) float xs[64*52];
  __shared__ float iv1[64];
  int t = threadIdx.x;
  int bIdx = blockIdx.x;
  int b = bIdx / HWc, hw = bIdx % HWc;
  size_t sbase = ((size_t)b*Cc*HWc + hw)*Ll;
  const float* txb = tx + sbase;
  const float* xb  = x  + sbase;
  const float* tgs = tgsite + (size_t)bIdx*3072;
  float m1 = gmin[0], m2 = gmin[1];
  #pragma unroll
  for (int k = 0; k < 3; ++k){
    int q = t + (k << 8);
    int c = q / 12, v = (q % 12) << 2;
    *(float4*)&txt[c*52+v] = *(const float4*)(txb + (size_t)c*HWL + v);
    *(float4*)&xs [c*52+v] = *(const float4*)(xb  + (size_t)c*HWL + v);
    *(float4*)&tgt[c*52+v] = *(const float4*)(tgs + (q << 2));
  }
  if (t < 64) iv1[t] = 1.f/(rowsum[b*64 + t] - m1*CNT1f);
  float invd2 = 1.f/(s2v[b] - m2*CNT2f);
  __syncthreads();
  // At accumulation in registers
  int i0 = (t & 15) << 2, j0 = (t >> 4) << 2;
  float a00=0,a01=0,a02=0,a03=0,a10=0,a11=0,a12=0,a13=0;
  float a20=0,a21=0,a22=0,a23=0,a30=0,a31=0,a32=0,a33=0;
  #pragma unroll 4
  for (int l0 = 0; l0 < 48; l0 += 4){
    float4 x0 = *(const float4*)&txt[(i0+0)*52 + l0];
    float4 x1 = *(const float4*)&txt[(i0+1)*52 + l0];
    float4 x2 = *(const float4*)&txt[(i0+2)*52 + l0];
    float4 x3 = *(const float4*)&txt[(i0+3)*52 + l0];
    float4 g0 = *(const float4*)&tgt[(j0+0)*52 + l0];
    float4 g1 = *(const float4*)&tgt[(j0+1)*52 + l0];
    float4 g2 = *(const float4*)&tgt[(j0+2)*52 + l0];
    float4 g3 = *(const float4*)&tgt[(j0+3)*52 + l0];
    a00 += x0.x*g0.x + x0.y*g0.y + x0.z*g0.z + x0.w*g0.w;
    a01 += x0.x*g1.x + x0.y*g1.y + x0.z*g1.z + x0.w*g1.w;
    a02 += x0.x*g2.x + x0.y*g2.y + x0.z*g2.z + x0.w*g2.w;
    a03 += x0.x*g3.x + x0.y*g3.y + x0.z*g3.z + x0.w*g3.w;
    a10 += x1.x*g0.x + x1.y*g0.y + x1.z*g0.z + x1.w*g0.w;
    a11 += x1.x*g1.x + x1.y*g1.y + x1.z*g1.z + x1.w*g1.w;
    a12 += x1.x*g2.x + x1.y*g2.y + x1.z*g2.z + x1.w*g2.w;
    a13 += x1.x*g3.x + x1.y*g3.y + x1.z*g3.z + x1.w*g3.w;
    a20 += x2.x*g0.x + x2.y*g0.y + x2.z*g0.z + x2.w*g0.w;
    a21 += x2.x*g1.x + x2.y*g1.y + x2.z*g1.z + x2.w*g1.w;
    a22 += x2.x*g2.x + x2.y*g2.y + x2.z*g2.z + x2.w*g2.w;
    a23 += x2.x*g3.x + x2.y*g3.y + x2.z*g3.z + x2.w*g3.w;
    a30 += x3.x*g0.x + x3.y*g0.y + x3.z*g0.z + x3.w*g0.w;
    a31 += x3.x*g1.x + x3.y*g1.y + x3.z*g1.z + x3.w*g1.w;
    a32 += x3.x*g2.x + x3.y*g2.y + x3.z*g2.z + x3.w*g2.w;
    a33 += x3.x*g3.x + x3.y*g3.y + x3.z*g3.z + x3.w*g3.w;
  }
  // p = (tx*tg - m1)*iv1[c]*x  (reads txt/tgt/xs, conflict-free)
  #pragma unroll
  for (int k = 0; k < 3; ++k){
    int q = t + (k << 8);
    int c = q / 12, l4 = (q % 12) << 2;
    float4 a = *(const float4*)&txt[c*52+l4];
    float4 g = *(const float4*)&tgt[c*52+l4];
    float4 xv = *(const float4*)&xs[c*52+l4];
    float s = iv1[c];
    float4 r = make_float4((a.x*g.x - m1)*s*xv.x, (a.y*g.y - m1)*s*xv.y,
                           (a.z*g.z - m1)*s*xv.z, (a.w*g.w - m1)*s*xv.w);
    *(float4*)(outp + sbase + (size_t)c*HWL + l4) = r;
  }
  __syncthreads();   // all txt reads done; safe to overwrite with At'
  float* At = txt;   // At'[c][j] = (At[c][j]-m2)*invd2, stride 52
  { float4 r = make_float4((a00-m2)*invd2,(a01-m2)*invd2,(a02-m2)*invd2,(a03-m2)*invd2);
    *(float4*)&At[(i0+0)*52 + j0] = r; }
  { float4 r = make_float4((a10-m2)*invd2,(a11-m2)*invd2,(a12-m2)*invd2,(a13-m2)*invd2);
    *(float4*)&At[(i0+1)*52 + j0] = r; }
  { float4 r = make_float4((a20-m2)*invd2,(a21-m2)*invd2,(a22-m2)*invd2,(a23-m2)*invd2);
    *(float4*)&At[(i0+2)*52 + j0] = r; }
  { float4 r = make_float4((a30-m2)*invd2,(a31-m2)*invd2,(a32-m2)*invd2,(a33-m2)*invd2);
    *(float4*)&At[(i0+3)*52 + j0] = r; }
  __syncthreads();
  // d[j,l] = sum_c At'[c][j]*x[c][l]
  if (t < 192){
    int jj = (t & 15) << 2, l0 = (t >> 4) << 2;
    float d00=0,d01=0,d02=0,d03=0,d10=0,d11=0,d12=0,d13=0;
    float d20=0,d21=0,d22=0,d23=0,d30=0,d31=0,d32=0,d33=0;
    #pragma unroll 4
    for (int cc = 0; cc < 64; ++cc){
      float4 av = *(const float4*)&At[cc*52 + jj];
      float4 xv = *(const float4*)&xs[cc*52 + l0];
      d00 += av.x*xv.x; d01 += av.x*xv.y; d02 += av.x*xv.z; d03 += av.x*xv.w;
      d10 += av.y*xv.x; d11 += av.y*xv.y; d12 += av.y*xv.z; d13 += av.y*xv.w;
      d20 += av.z*xv.x; d21 += av.z*xv.y; d22 += av.z*xv.z; d23 += av.z*xv.w;
      d30 += av.w*xv.x; d31 += av.w*xv.y; d32 += av.w*xv.z; d33 += av.w*xv.w;
    }
    { float4 r = make_float4(d00,d01,d02,d03);
      *(float4*)(outd + sbase + (size_t)(jj+0)*HWL + l0) = r; }
    { float4 r = make_float4(d10,d11,d12,d13);
      *(float4*)(outd + sbase + (size_t)(jj+1)*HWL + l0) = r; }
    { float4 r = make_float4(d20,d21,d22,d23);
      *(float4*)(outd + sbase + (size_t)(jj+2)*HWL + l0) = r; }
    { float4 r = make_float4(d30,d31,d32,d33);
      *(float4*)(outd + sbase + (size_t)(jj+3)*HWL + l0) = r; }
  }
}

extern "C" void kernel_launch(void* const* d_in, const int* in_sizes, int n_in,
                              void* d_out, int out_size, void* d_ws, size_t ws_size,
                              hipStream_t stream){
  (void)in_sizes; (void)n_in; (void)out_size; (void)ws_size;
  const float* x  = (const float*)d_in[0];
  const float* g  = (const float*)d_in[1];
  const float* W1 = (const float*)d_in[2];
  const float* b1 = (const float*)d_in[3];
  const float* W2 = (const float*)d_in[4];
  const float* b2 = (const float*)d_in[5];
  float* outp = (float*)d_out;
  float* outd = outp + (size_t)Bb*Cc*HWL;
  float* ws   = (float*)d_ws;
  float* txw    = ws;                               // 14,155,776 floats
  float* tghw   = txw + (size_t)Bb*Cc*HWL;          // 1,769,472
  float* tgsite = tghw + (size_t)Bb*Cc*SG;          // 14,155,776 (site-major tg)
  float* part_row = tgsite + (size_t)Bb*Cc*HWL;     // NBLK*64
  float* pm1 = part_row + (size_t)NBLK*64;          // NBLK
  float* pm2 = pm1 + NBLK;                          // NBLK
  float* ps2 = pm2 + NBLK;                          // NBLK
  float* rowsum = ps2 + NBLK;                       // 128
  float* gmin = rowsum + 128;                       // 2
  float* s2v  = gmin + 2;                           // 2

  hipLaunchKernelGGL(conv_k, dim3(Bb*(SG/64)), dim3(256), 0, stream, g, W2, b2, tghw, SG);
  hipLaunchKernelGGL(conv_k, dim3(Bb*(HWL/64)), dim3(256), 0, stream, x, W1, b1, txw, HWL);
  hipLaunchKernelGGL(reduce_k, dim3(NBLK), dim3(256), 0, stream, txw, tghw, tgsite,
                     part_row, pm1, pm2, ps2);
  hipLaunchKernelGGL(reduce2_k, dim3(130), dim3(256), 0, stream, part_row, pm1, pm2, ps2,
                     rowsum, gmin, s2v);
  hipLaunchKernelGGL(final_k, dim3(NBLK), dim3(256), 0, stream, x, txw, tgsite,
                     gmin, rowsum, s2v, outp, outd);
}

// Round 3
// 306.342 us; speedup vs baseline: 1.1757x; 1.0801x over previous
//
#include <hip/hip_runtime.h>

#define Bb 2
#define Cc 64
#define Hh 48
#define Ww 48
#define Ll 48
#define HWc (Hh*Ww)          /* 2304 */
#define HWL (HWc*Ll)         /* 110592 */
#define GHh 24
#define SG (GHh*GHh*GHh)     /* 13824 */
#define NBLK (Bb*HWc)        /* 4608 */
#define CNT1f 110592.0f
#define CNT2f 9437184.0f     /* HW*C*C */

// half-pixel trilinear taps for 24 -> 48 (matches jax.image.resize 'trilinear')
__device__ __forceinline__ void interp1(int i, int& a, int& b, float& f){
  float src = i*0.5f - 0.25f;
  float fl = floorf(src);
  f = src - fl;
  int i0 = (int)fl;
  a = i0 < 0 ? 0 : i0;
  int i1 = i0 + 1;
  b = i1 > (GHh-1) ? (GHh-1) : i1;
}

// out[b,o,s] = sum_c W[o,c]*in[b,c,s] + bias[o]
__global__ __launch_bounds__(256) void conv_k(const float* __restrict__ in,
    const float* __restrict__ Wm, const float* __restrict__ bias,
    float* __restrict__ out, int S){
  __shared__ __align__(16) float Wl[64][68];   // Wl[c][o]
  __shared__ __align__(16) float xl[64][68];   // xl[c][s]
  int t = threadIdx.x;
  int ntile = S >> 6;
  int b  = blockIdx.x / ntile;
  int s0 = (blockIdx.x % ntile) << 6;
  for (int q = t; q < 4096; q += 256){
    int o = q >> 6, c = q & 63;
    Wl[c][o] = Wm[q];
  }
  const float* inb = in + (size_t)b*Cc*S + s0;
  for (int q = t; q < 1024; q += 256){
    int c = q >> 4, v = (q & 15) << 2;
    float4 val = *(const float4*)(inb + (size_t)c*S + v);
    *(float4*)&xl[c][v] = val;
  }
  __syncthreads();
  int o0 = (t & 15) << 2, s1 = (t >> 4) << 2;
  float a00=0,a01=0,a02=0,a03=0,a10=0,a11=0,a12=0,a13=0;
  float a20=0,a21=0,a22=0,a23=0,a30=0,a31=0,a32=0,a33=0;
  #pragma unroll 8
  for (int c = 0; c < 64; ++c){
    float4 wv = *(const float4*)&Wl[c][o0];
    float4 xv = *(const float4*)&xl[c][s1];
    a00 += wv.x*xv.x; a01 += wv.x*xv.y; a02 += wv.x*xv.z; a03 += wv.x*xv.w;
    a10 += wv.y*xv.x; a11 += wv.y*xv.y; a12 += wv.y*xv.z; a13 += wv.y*xv.w;
    a20 += wv.z*xv.x; a21 += wv.z*xv.y; a22 += wv.z*xv.z; a23 += wv.z*xv.w;
    a30 += wv.w*xv.x; a31 += wv.w*xv.y; a32 += wv.w*xv.z; a33 += wv.w*xv.w;
  }
  float* ob = out + (size_t)b*Cc*S + s0 + s1;
  float b0 = bias[o0+0], b1v = bias[o0+1], b2v = bias[o0+2], b3 = bias[o0+3];
  { float4 r = make_float4(a00+b0,a01+b0,a02+b0,a03+b0); *(float4*)(ob + (size_t)(o0+0)*S) = r; }
  { float4 r = make_float4(a10+b1v,a11+b1v,a12+b1v,a13+b1v); *(float4*)(ob + (size_t)(o0+1)*S) = r; }
  { float4 r = make_float4(a20+b2v,a21+b2v,a22+b2v,a23+b2v); *(float4*)(ob + (size_t)(o0+2)*S) = r; }
  { float4 r = make_float4(a30+b3,a31+b3,a32+b3,a33+b3); *(float4*)(ob + (size_t)(o0+3)*S) = r; }
}

// G-fold: G[k][c] = sum_l w(l,k)*txt[c][l] — transposed 48->24 interp weights.
// Weights: k=0: (1,.75,.25)@l=0..2; k=23: (.25,.75,1)@l=45..47;
// else (.25,.75,.75,.25)@l=2k-1..2k+2.
__device__ __forceinline__ void g_fold(const float* __restrict__ txt,
    float* __restrict__ G, int t){
  int c = t >> 2, kb = (t & 3)*6;
  const float* T = &txt[c*52];
  #pragma unroll
  for (int i = 0; i < 6; ++i){
    int k = kb + i;
    float v;
    if (k == 0)       v = T[0] + 0.75f*T[1] + 0.25f*T[2];
    else if (k == 23) v = 0.25f*T[45] + 0.75f*T[46] + T[47];
    else              v = 0.25f*T[2*k-1] + 0.75f*T[2*k]
                        + 0.75f*T[2*k+1] + 0.25f*T[2*k+2];
    G[k*68 + c] = v;
  }
}

// one block per (b,h,w) site. Computes per-site bilinear row M[24][c] from
// half-res tgh, the l-fold G, all partials (rowsum, mins, s2), and stores M
// site-major for final_k. tg full-res is never materialized.
__global__ __launch_bounds__(256) void reduce_k(const float* __restrict__ tx,
    const float* __restrict__ tgh, float* __restrict__ msite,
    float* __restrict__ part_row, float* __restrict__ pm1,
    float* __restrict__ pm2, float* __restrict__ ps2){
  __shared__ __align__(16) float sh[7224];
  float* txt = sh;            // [64][52]
  float* M   = sh + 3328;     // [24][68]  k-major
  float* G   = sh + 4960;     // [24][68]  k-major
  float* red = sh + 6592;     // [512]
  float* sxg = sh + 7104;     // [48]
  float* CM  = sh + 7152;     // [24]
  float* SX  = sh + 7176;     // [48]
  int t = threadIdx.x;
  int bIdx = blockIdx.x;
  int b = bIdx / HWc, hw = bIdx % HWc;
  int h = hw / Ww, w = hw % Ww;
  int ha, hb; float fh; interp1(h, ha, hb, fh);
  int wa, wb; float fw; interp1(w, wa, wb, fw);
  float omh = 1.f - fh, omw = 1.f - fw;
  const float* txb = tx + ((size_t)b*Cc*HWc + hw)*Ll;
  #pragma unroll
  for (int k = 0; k < 3; ++k){
    int q = t + (k << 8);
    int c = q / 12, v = (q % 12) << 2;
    *(float4*)&txt[c*52+v] = *(const float4*)(txb + (size_t)c*HWL + v);
  }
  // M[k][c] = bilinear(h,w) of tgh (h-lerp then w-lerp, same as before)
  const float* gb = tgh + (size_t)b*Cc*SG;
  for (int u = t; u < 384; u += 256){
    int c = u / 6, s4 = (u % 6) << 2;
    const float* gc = gb + (size_t)c*SG;
    float4 vaa = *(const float4*)(gc + ha*576 + wa*24 + s4);
    float4 vba = *(const float4*)(gc + hb*576 + wa*24 + s4);
    float4 vab = *(const float4*)(gc + ha*576 + wb*24 + s4);
    float4 vbb = *(const float4*)(gc + hb*576 + wb*24 + s4);
    M[(s4+0)*68 + c] = omw*(omh*vaa.x + fh*vba.x) + fw*(omh*vab.x + fh*vbb.x);
    M[(s4+1)*68 + c] = omw*(omh*vaa.y + fh*vba.y) + fw*(omh*vab.y + fh*vbb.y);
    M[(s4+2)*68 + c] = omw*(omh*vaa.z + fh*vba.z) + fw*(omh*vab.z + fh*vbb.z);
    M[(s4+3)*68 + c] = omw*(omh*vaa.w + fh*vba.w) + fw*(omh*vab.w + fh*vbb.w);
  }
  __syncthreads();
  g_fold(txt, G, t);
  if (t < 24){
    float s = 0.f;
    #pragma unroll 8
    for (int c = 0; c < 64; ++c) s += M[t*68 + c];
    CM[t] = s;
  }
  if (t >= 192 && t < 240){
    int l = t - 192;
    float s = 0.f;
    #pragma unroll 8
    for (int c = 0; c < 64; ++c) s += txt[c*52 + l];
    SX[l] = s;
  }
  __syncthreads();
  // per-channel product sums + global min of products (tg expanded on the fly)
  int c = t & 63, lg = t >> 6;
  float psum = 0.f, pmin = 3.4e38f;
  const float* Trow = &txt[c*52];
  #pragma unroll
  for (int li = 0; li < 12; ++li){
    int l = lg*12 + li;
    int la, lb; float fl; interp1(l, la, lb, fl);
    float tgv = (1.f-fl)*M[la*68 + c] + fl*M[lb*68 + c];
    float prod = Trow[l]*tgv;
    psum += prod;
    pmin = fminf(pmin, prod);
  }
  red[t] = psum;
  if (t < 48){
    int la, lb; float fl; interp1(t, la, lb, fl);
    sxg[t] = SX[t] * ((1.f-fl)*CM[la] + fl*CM[lb]);
  }
  // store M site-major for final_k (contiguous, coalesced)
  float* msb = msite + (size_t)bIdx*1536;
  for (int u = t; u < 384; u += 256){
    int k = u >> 4, c4 = (u & 15) << 2;
    float4 mv;
    mv.x = M[k*68+c4+0]; mv.y = M[k*68+c4+1];
    mv.z = M[k*68+c4+2]; mv.w = M[k*68+c4+3];
    *(float4*)(msb + (u << 2)) = mv;
  }
  // At[i][j] = sum_k G[k][i]*M[k][j] — lane-contiguous / broadcast, conflict-free
  int i0 = (t & 15) << 2, j0 = (t >> 4) << 2;
  float a00=0,a01=0,a02=0,a03=0,a10=0,a11=0,a12=0,a13=0;
  float a20=0,a21=0,a22=0,a23=0,a30=0,a31=0,a32=0,a33=0;
  #pragma unroll 4
  for (int k = 0; k < 24; ++k){
    float4 gv = *(const float4*)&G[k*68 + i0];
    float4 mv = *(const float4*)&M[k*68 + j0];
    a00 += gv.x*mv.x; a01 += gv.x*mv.y; a02 += gv.x*mv.z; a03 += gv.x*mv.w;
    a10 += gv.y*mv.x; a11 += gv.y*mv.y; a12 += gv.y*mv.z; a13 += gv.y*mv.w;
    a20 += gv.z*mv.x; a21 += gv.z*mv.y; a22 += gv.z*mv.z; a23 += gv.z*mv.w;
    a30 += gv.w*mv.x; a31 += gv.w*mv.y; a32 += gv.w*mv.z; a33 += gv.w*mv.w;
  }
  float amin = fminf(fminf(fminf(a00,a01),fminf(a02,a03)),
               fminf(fminf(fminf(a10,a11),fminf(a12,a13)),
               fminf(fminf(fminf(a20,a21),fminf(a22,a23)),
                     fminf(fminf(a30,a31),fminf(a32,a33)))));
  __syncthreads();            // red (psum) fully written
  if (t < 64) part_row[(size_t)bIdx*64 + t] = red[t]+red[t+64]+red[t+128]+red[t+192];
  __syncthreads();            // part_row reads done before red reuse
  red[t] = pmin; red[256+t] = amin;
  __syncthreads();
  if (t < 128){
    red[t] = fminf(red[t], red[t+128]);
    red[256+t] = fminf(red[256+t], red[384+t]);
  }
  __syncthreads();
  if (t < 64){
    float v1 = fminf(red[t], red[t+64]);
    float v2 = fminf(red[256+t], red[320+t]);
    #pragma unroll
    for (int off = 32; off; off >>= 1){
      v1 = fminf(v1, __shfl_down(v1, off));
      v2 = fminf(v2, __shfl_down(v2, off));
    }
    if (t == 0){
      pm1[bIdx] = v1; pm2[bIdx] = v2;
      float tot = 0.f;
      #pragma unroll
      for (int l = 0; l < 48; ++l) tot += sxg[l];
      ps2[bIdx] = tot;
    }
  }
}

// parallel second-stage reduction: 130 blocks (unchanged)
__global__ __launch_bounds__(256) void reduce2_k(const float* __restrict__ part_row,
    const float* __restrict__ pm1, const float* __restrict__ pm2,
    const float* __restrict__ ps2, float* __restrict__ rowsum,
    float* __restrict__ gmin, float* __restrict__ s2v){
  __shared__ float red[512];
  int t = threadIdx.x, blk = blockIdx.x;
  if (blk < 128){
    int b = blk >> 6, c = blk & 63;
    const float* src = part_row + (size_t)b*HWc*64 + c;
    float s = 0.f;
    #pragma unroll
    for (int k = 0; k < 9; ++k){
      int i = t + (k << 8);
      s += src[(size_t)i*64];
    }
    red[t] = s; __syncthreads();
    for (int sgap = 128; sgap >= 64; sgap >>= 1){
      if (t < sgap) red[t] += red[t+sgap];
      __syncthreads();
    }
    if (t < 64){
      float v = red[t];
      #pragma unroll
      for (int off = 32; off; off >>= 1) v += __shfl_down(v, off);
      if (t == 0) rowsum[blk] = v;
    }
  } else if (blk == 128){
    float m1 = 3.4e38f, m2 = 3.4e38f;
    for (int i = t; i < NBLK; i += 256){ m1 = fminf(m1, pm1[i]); m2 = fminf(m2, pm2[i]); }
    red[t] = m1; red[256+t] = m2; __syncthreads();
    for (int s = 128; s >= 1; s >>= 1){
      if (t < s){ red[t] = fminf(red[t], red[t+s]); red[256+t] = fminf(red[256+t], red[256+t+s]); }
      __syncthreads();
    }
    if (t == 0){ gmin[0] = red[0]; gmin[1] = red[256]; }
  } else {
    float sa = 0.f, sb = 0.f;
    for (int i = t; i < HWc; i += 256){ sa += ps2[i]; sb += ps2[HWc + i]; }
    red[t] = sa; red[256+t] = sb; __syncthreads();
    for (int s = 128; s >= 1; s >>= 1){
      if (t < s){ red[t] += red[t+s]; red[256+t] += red[256+t+s]; }
      __syncthreads();
    }
    if (t == 0){ s2v[0] = red[0]; s2v[1] = red[256]; }
  }
}

// one block per (b,h,w): p and d. At recomputed from G,M (K=24, conflict-free);
// tg expanded on the fly from M for p; At' aliases txt after p.
__global__ __launch_bounds__(256) void final_k(const float* __restrict__ x,
    const float* __restrict__ tx, const float* __restrict__ msite,
    const float* __restrict__ gmin, const float* __restrict__ rowsum,
    const float* __restrict__ s2v, float* __restrict__ outp, float* __restrict__ outd){
  __shared__ __align__(16) float sh[9984];
  float* txt = sh;            // [64][52]  (At' aliases this after p)
  float* xs  = sh + 3328;     // [64][52]
  float* M   = sh + 6656;     // [24][68]
  float* G   = sh + 8288;     // [24][68]
  float* iv1 = sh + 9920;     // [64]
  int t = threadIdx.x;
  int bIdx = blockIdx.x;
  int b = bIdx / HWc, hw = bIdx % HWc;
  size_t sbase = ((size_t)b*Cc*HWc + hw)*Ll;
  const float* txb = tx + sbase;
  const float* xb  = x  + sbase;
  float m1 = gmin[0], m2 = gmin[1];
  #pragma unroll
  for (int k = 0; k < 3; ++k){
    int q = t + (k << 8);
    int c = q / 12, v = (q % 12) << 2;
    *(float4*)&txt[c*52+v] = *(const float4*)(txb + (size_t)c*HWL + v);
    *(float4*)&xs [c*52+v] = *(const float4*)(xb  + (size_t)c*HWL + v);
  }
  const float* msb = msite + (size_t)bIdx*1536;
  for (int u = t; u < 384; u += 256){
    float4 mv = *(const float4*)(msb + (u << 2));
    int k = u >> 4, c4 = (u & 15) << 2;
    *(float4*)&M[k*68 + c4] = mv;
  }
  if (t < 64) iv1[t] = 1.f/(rowsum[b*64 + t] - m1*CNT1f);
  float invd2 = 1.f/(s2v[b] - m2*CNT2f);
  __syncthreads();
  g_fold(txt, G, t);
  __syncthreads();
  // At[i][j] = sum_k G[k][i]*M[k][j]
  int i0 = (t & 15) << 2, j0 = (t >> 4) << 2;
  float a00=0,a01=0,a02=0,a03=0,a10=0,a11=0,a12=0,a13=0;
  float a20=0,a21=0,a22=0,a23=0,a30=0,a31=0,a32=0,a33=0;
  #pragma unroll 4
  for (int k = 0; k < 24; ++k){
    float4 gv = *(const float4*)&G[k*68 + i0];
    float4 mv = *(const float4*)&M[k*68 + j0];
    a00 += gv.x*mv.x; a01 += gv.x*mv.y; a02 += gv.x*mv.z; a03 += gv.x*mv.w;
    a10 += gv.y*mv.x; a11 += gv.y*mv.y; a12 += gv.y*mv.z; a13 += gv.y*mv.w;
    a20 += gv.z*mv.x; a21 += gv.z*mv.y; a22 += gv.z*mv.z; a23 += gv.z*mv.w;
    a30 += gv.w*mv.x; a31 += gv.w*mv.y; a32 += gv.w*mv.z; a33 += gv.w*mv.w;
  }
  // p = (tx*tg - m1)*iv1[c]*x, tg expanded from M rows (same lerp as reduce_k)
  #pragma unroll
  for (int k = 0; k < 3; ++k){
    int q = t + (k << 8);
    int c = q / 12, l4 = (q % 12) << 2;
    float4 a  = *(const float4*)&txt[c*52+l4];
    float4 xv = *(const float4*)&xs [c*52+l4];
    float s = iv1[c];
    float4 r;
    {
      int la, lb; float fl; interp1(l4+0, la, lb, fl);
      float tgv = (1.f-fl)*M[la*68+c] + fl*M[lb*68+c];
      r.x = (a.x*tgv - m1)*s*xv.x;
    }
    {
      int la, lb; float fl; interp1(l4+1, la, lb, fl);
      float tgv = (1.f-fl)*M[la*68+c] + fl*M[lb*68+c];
      r.y = (a.y*tgv - m1)*s*xv.y;
    }
    {
      int la, lb; float fl; interp1(l4+2, la, lb, fl);
      float tgv = (1.f-fl)*M[la*68+c] + fl*M[lb*68+c];
      r.z = (a.z*tgv - m1)*s*xv.z;
    }
    {
      int la, lb; float fl; interp1(l4+3, la, lb, fl);
      float tgv = (1.f-fl)*M[la*68+c] + fl*M[lb*68+c];
      r.w = (a.w*tgv - m1)*s*xv.w;
    }
    *(float4*)(outp + sbase + (size_t)c*HWL + l4) = r;
  }
  __syncthreads();   // txt reads (p) done; safe to overwrite with At'
  float* At = txt;   // At'[c][j] = (At[c][j]-m2)*invd2, stride 52
  { float4 r = make_float4((a00-m2)*invd2,(a01-m2)*invd2,(a02-m2)*invd2,(a03-m2)*invd2);
    *(float4*)&At[(i0+0)*52 + j0] = r; }
  { float4 r = make_float4((a10-m2)*invd2,(a11-m2)*invd2,(a12-m2)*invd2,(a13-m2)*invd2);
    *(float4*)&At[(i0+1)*52 + j0] = r; }
  { float4 r = make_float4((a20-m2)*invd2,(a21-m2)*invd2,(a22-m2)*invd2,(a23-m2)*invd2);
    *(float4*)&At[(i0+2)*52 + j0] = r; }
  { float4 r = make_float4((a30-m2)*invd2,(a31-m2)*invd2,(a32-m2)*invd2,(a33-m2)*invd2);
    *(float4*)&At[(i0+3)*52 + j0] = r; }
  __syncthreads();
  // d[j,l] = sum_c At'[c][j]*x[c][l]
  if (t < 192){
    int jj = (t & 15) << 2, l0 = (t >> 4) << 2;
    float d00=0,d01=0,d02=0,d03=0,d10=0,d11=0,d12=0,d13=0;
    float d20=0,d21=0,d22=0,d23=0,d30=0,d31=0,d32=0,d33=0;
    #pragma unroll 4
    for (int cc = 0; cc < 64; ++cc){
      float4 av = *(const float4*)&At[cc*52 + jj];
      float4 xv = *(const float4*)&xs[cc*52 + l0];
      d00 += av.x*xv.x; d01 += av.x*xv.y; d02 += av.x*xv.z; d03 += av.x*xv.w;
      d10 += av.y*xv.x; d11 += av.y*xv.y; d12 += av.y*xv.z; d13 += av.y*xv.w;
      d20 += av.z*xv.x; d21 += av.z*xv.y; d22 += av.z*xv.z; d23 += av.z*xv.w;
      d30 += av.w*xv.x; d31 += av.w*xv.y; d32 += av.w*xv.z; d33 += av.w*xv.w;
    }
    { float4 r = make_float4(d00,d01,d02,d03);
      *(float4*)(outd + sbase + (size_t)(jj+0)*HWL + l0) = r; }
    { float4 r = make_float4(d10,d11,d12,d13);
      *(float4*)(outd + sbase + (size_t)(jj+1)*HWL + l0) = r; }
    { float4 r = make_float4(d20,d21,d22,d23);
      *(float4*)(outd + sbase + (size_t)(jj+2)*HWL + l0) = r; }
    { float4 r = make_float4(d30,d31,d32,d33);
      *(float4*)(outd + sbase + (size_t)(jj+3)*HWL + l0) = r; }
  }
}

extern "C" void kernel_launch(void* const* d_in, const int* in_sizes, int n_in,
                              void* d_out, int out_size, void* d_ws, size_t ws_size,
                              hipStream_t stream){
  (void)in_sizes; (void)n_in; (void)out_size; (void)ws_size;
  const float* x  = (const float*)d_in[0];
  const float* g  = (const float*)d_in[1];
  const float* W1 = (const float*)d_in[2];
  const float* b1 = (const float*)d_in[3];
  const float* W2 = (const float*)d_in[4];
  const float* b2 = (const float*)d_in[5];
  float* outp = (float*)d_out;
  float* outd = outp + (size_t)Bb*Cc*HWL;
  float* ws   = (float*)d_ws;
  float* txw    = ws;                               // 14,155,776 floats
  float* tghw   = txw + (size_t)Bb*Cc*HWL;          // 1,769,472
  float* msite  = tghw + (size_t)Bb*Cc*SG;          // NBLK*1536 = 7,077,888
  float* part_row = msite + (size_t)NBLK*1536;      // NBLK*64
  float* pm1 = part_row + (size_t)NBLK*64;          // NBLK
  float* pm2 = pm1 + NBLK;                          // NBLK
  float* ps2 = pm2 + NBLK;                          // NBLK
  float* rowsum = ps2 + NBLK;                       // 128
  float* gmin = rowsum + 128;                       // 2
  float* s2v  = gmin + 2;                           // 2

  hipLaunchKernelGGL(conv_k, dim3(Bb*(SG/64)), dim3(256), 0, stream, g, W2, b2, tghw, SG);
  hipLaunchKernelGGL(conv_k, dim3(Bb*(HWL/64)), dim3(256), 0, stream, x, W1, b1, txw, HWL);
  hipLaunchKernelGGL(reduce_k, dim3(NBLK), dim3(256), 0, stream, txw, tghw, msite,
                     part_row, pm1, pm2, ps2);
  hipLaunchKernelGGL(reduce2_k, dim3(130), dim3(256), 0, stream, part_row, pm1, pm2, ps2,
                     rowsum, gmin, s2v);
  hipLaunchKernelGGL(final_k, dim3(NBLK), dim3(256), 0, stream, x, txw, msite,
                     gmin, rowsum, s2v, outp, outd);
}